// Round 2
// baseline (253.550 us; speedup 1.0000x reference)
//
#include <hip/hip_runtime.h>
#include <hip/hip_bf16.h>

// Problem constants (from reference)
#define BATCH   64
#define NMEL    80
#define TFRAME  1000
#define NDEC    1000
#define TENC    200
#define NSPK    100
#define NAUG    10

// Element counts
#define N_MEL   (BATCH * NMEL * TFRAME)     // 5,120,000
#define N_GATE  (BATCH * TFRAME)            // 64,000
#define N_ALIGN (BATCH * NDEC * TENC)       // 12,800,000

// 4-element (16 B fp32) vector units
#define U_MEL   (N_MEL / 4)                 // 1,280,000
#define U_GATE  (N_GATE / 4)                // 16,000
#define U_ALIGN (N_ALIGN / 4)               // 3,200,000
#define U_MG    (U_MEL + U_GATE)            // 1,296,000
#define U_TOTAL (U_MG + U_ALIGN)            // 4,496,000

#define MAIN_BLOCKS 2048
#define BLOCK 256

// ws layout (floats): [0]=mel_sum [1]=gate_sum [2]=align_sum [3]=spk_sum [4]=aug_sum [5]=counter(u32)

__device__ __forceinline__ float waveReduceSum(float v) {
#pragma unroll
    for (int o = 32; o > 0; o >>= 1) v += __shfl_down(v, o, 64);
    return v;
}

__global__ __launch_bounds__(BLOCK) void tacotron2_loss_kernel(
    const float* __restrict__ mel_out,
    const float* __restrict__ mel_post,
    const float* __restrict__ gate_out,
    const float* __restrict__ align,
    const float* __restrict__ spk_out,
    const float* __restrict__ aug_out,
    const float* __restrict__ mel_tgt,
    const float* __restrict__ gate_tgt,
    const float* __restrict__ spk_tgt,
    const float* __restrict__ aug_tgt,
    float* __restrict__ out,
    float* __restrict__ ws)
{
    float mel_s = 0.f, gate_s = 0.f, align_s = 0.f;
    const int bid = blockIdx.x;

    if (bid < MAIN_BLOCKS) {
        const int nthreads = MAIN_BLOCKS * BLOCK;
        const int tid = bid * BLOCK + threadIdx.x;
        for (int u = tid; u < U_TOTAL; u += nthreads) {
            if (u < U_MEL) {
                float4 a = ((const float4*)mel_out)[u];
                float4 p = ((const float4*)mel_post)[u];
                float4 t = ((const float4*)mel_tgt)[u];
                float d;
                d = a.x - t.x; mel_s = fmaf(d, d, mel_s);
                d = a.y - t.y; mel_s = fmaf(d, d, mel_s);
                d = a.z - t.z; mel_s = fmaf(d, d, mel_s);
                d = a.w - t.w; mel_s = fmaf(d, d, mel_s);
                d = p.x - t.x; mel_s = fmaf(d, d, mel_s);
                d = p.y - t.y; mel_s = fmaf(d, d, mel_s);
                d = p.z - t.z; mel_s = fmaf(d, d, mel_s);
                d = p.w - t.w; mel_s = fmaf(d, d, mel_s);
            } else if (u < U_MG) {
                int v = u - U_MEL;
                float4 x = ((const float4*)gate_out)[v];
                float4 y = ((const float4*)gate_tgt)[v];
                float fx[4] = {x.x, x.y, x.z, x.w};
                float fy[4] = {y.x, y.y, y.z, y.w};
#pragma unroll
                for (int j = 0; j < 4; j++) {
                    float xx = fx[j];
                    // softplus(x) = max(x,0) + log1p(exp(-|x|))
                    float sp = fmaxf(xx, 0.f) + log1pf(__expf(-fabsf(xx)));
                    gate_s += sp - xx * fy[j];
                }
            } else {
                int v = u - U_MG;
                float4 a = ((const float4*)align)[v];
                float fa[4] = {a.x, a.y, a.z, a.w};
                int e = v * 4;
                int t0 = e % TENC;                 // 4 consecutive t, same n (200 % 4 == 0)
                int n = (e / TENC) % NDEC;
                float nf = (float)n * (1.0f / (float)NDEC);
#pragma unroll
                for (int j = 0; j < 4; j++) {
                    float tf_ = (float)(t0 + j) * (1.0f / (float)TENC);
                    float d = nf - tf_;
                    float g = 1.0f - __expf(d * d * -2.5f);   // 1/K_ALIGN = 2.5
                    align_s = fmaf(fa[j], g, align_s);
                }
            }
        }
    } else {
        // CE block: threads 0..63 -> speaker rows, 64..127 -> augment rows
        const int t = threadIdx.x;
        if (t < 64) {
            const int r = t;
            const float* row = spk_out + r * NSPK;
            float mx = -1e30f;
            for (int c = 0; c < NSPK; c++) mx = fmaxf(mx, row[c]);
            float se = 0.f;
            for (int c = 0; c < NSPK; c++) se += __expf(row[c] - mx);
            const float* trow = spk_tgt + r * NSPK;
            float tm = -1e30f; int lab = 0;
            for (int c = 0; c < NSPK; c++) {
                float v = trow[c];
                if (v > tm) { tm = v; lab = c; }
            }
            float loss = -(row[lab] - mx - __logf(se));
            atomicAdd(&ws[3], loss);
        } else if (t < 128) {
            const int r = t - 64;
            const float* row = aug_out + r * NAUG;
            float mx = -1e30f;
            for (int c = 0; c < NAUG; c++) mx = fmaxf(mx, row[c]);
            float se = 0.f;
            for (int c = 0; c < NAUG; c++) se += __expf(row[c] - mx);
            const float* trow = aug_tgt + r * NAUG;
            float tm = -1e30f; int lab = 0;
            for (int c = 0; c < NAUG; c++) {
                float v = trow[c];
                if (v > tm) { tm = v; lab = c; }
            }
            float loss = -(row[lab] - mx - __logf(se));
            atomicAdd(&ws[4], loss);
        }
    }

    // Block reduction of the three main sums (CE block contributes zeros)
    __shared__ float smem[12];
    const int lane = threadIdx.x & 63;
    const int wid = threadIdx.x >> 6;
    mel_s = waveReduceSum(mel_s);
    gate_s = waveReduceSum(gate_s);
    align_s = waveReduceSum(align_s);
    if (lane == 0) {
        smem[wid * 3 + 0] = mel_s;
        smem[wid * 3 + 1] = gate_s;
        smem[wid * 3 + 2] = align_s;
    }
    __syncthreads();

    if (threadIdx.x == 0) {
        float m = 0.f, g = 0.f, al = 0.f;
#pragma unroll
        for (int w = 0; w < 4; w++) {
            m += smem[w * 3 + 0];
            g += smem[w * 3 + 1];
            al += smem[w * 3 + 2];
        }
        atomicAdd(&ws[0], m);
        atomicAdd(&ws[1], g);
        atomicAdd(&ws[2], al);
        __threadfence();
        unsigned int old = atomicAdd((unsigned int*)(ws + 5), 1u);
        if (old == gridDim.x - 1) {
            // Last block: all accumulators final (atomic reads for device coherence)
            float mel_sum   = atomicAdd(&ws[0], 0.f);
            float gate_sum  = atomicAdd(&ws[1], 0.f);
            float align_sum = atomicAdd(&ws[2], 0.f);
            float spk_sum   = atomicAdd(&ws[3], 0.f);
            float aug_sum   = atomicAdd(&ws[4], 0.f);

            float mel_loss  = mel_sum  * (1.0f / (float)N_MEL);
            float gate_loss = gate_sum * (1.0f / (float)N_GATE);
            float spk_loss  = spk_sum  * (1.0f / (float)BATCH);
            float aug_loss  = aug_sum  * (1.0f / (float)BATCH);
            float align_loss = fabsf(align_sum) * 0.0005f;
            float tmp = mel_loss + gate_loss;
            float total = 10.0f * tmp + 0.1f * (spk_loss + aug_loss) + align_loss;

            out[0] = total;
            out[1] = tmp;
            out[2] = spk_loss;
            out[3] = aug_loss;
            out[4] = align_loss;
        }
    }
}

extern "C" void kernel_launch(void* const* d_in, const int* in_sizes, int n_in,
                              void* d_out, int out_size, void* d_ws, size_t ws_size,
                              hipStream_t stream) {
    const float* mel_out  = (const float*)d_in[0];
    const float* mel_post = (const float*)d_in[1];
    const float* gate_out = (const float*)d_in[2];
    const float* align    = (const float*)d_in[3];
    const float* spk_out  = (const float*)d_in[4];
    const float* aug_out  = (const float*)d_in[5];
    const float* mel_tgt  = (const float*)d_in[6];
    const float* gate_tgt = (const float*)d_in[7];
    const float* spk_tgt  = (const float*)d_in[8];
    const float* aug_tgt  = (const float*)d_in[9];
    // d_in[10] = step (unused by the loss values)

    float* ws = (float*)d_ws;
    float* out = (float*)d_out;

    // Zero accumulators + completion counter (harness poisons ws with 0xAA)
    hipMemsetAsync(d_ws, 0, 8 * sizeof(float), stream);

    tacotron2_loss_kernel<<<dim3(MAIN_BLOCKS + 1), dim3(BLOCK), 0, stream>>>(
        mel_out, mel_post, gate_out, align, spk_out, aug_out,
        mel_tgt, gate_tgt, spk_tgt, aug_tgt, out, ws);
}

// Round 3
// 223.634 us; speedup vs baseline: 1.1338x; 1.1338x over previous
//
#include <hip/hip_runtime.h>
#include <hip/hip_bf16.h>

// Problem constants (from reference)
#define BATCH   64
#define NMEL    80
#define TFRAME  1000
#define NDEC    1000
#define TENC    200
#define NSPK    100
#define NAUG    10

// Element counts
#define N_MEL   (BATCH * NMEL * TFRAME)     // 5,120,000
#define N_GATE  (BATCH * TFRAME)            // 64,000
#define N_ALIGN (BATCH * NDEC * TENC)       // 12,800,000

// 4-element (16 B fp32) vector units
#define U_MEL   (N_MEL / 4)                 // 1,280,000
#define U_GATE  (N_GATE / 4)                // 16,000
#define U_ALIGN (N_ALIGN / 4)               // 3,200,000
#define U_MG    (U_MEL + U_GATE)            // 1,296,000
#define U_TOTAL (U_MG + U_ALIGN)            // 4,496,000

#define MAIN_BLOCKS 2048
#define BLOCK 256

// ws layout (floats), 64 B (16-float) spacing so each atomic target owns a cacheline:
//  [0]=mel_sum  [16]=gate_sum  [32]=align_sum  [48]=spk_sum  [64]=aug_sum  [80]=counter(u32)
#define WS_MEL   0
#define WS_GATE  16
#define WS_ALIGN 32
#define WS_SPK   48
#define WS_AUG   64
#define WS_CNT   80

__device__ __forceinline__ float waveReduceSum(float v) {
#pragma unroll
    for (int o = 32; o > 0; o >>= 1) v += __shfl_down(v, o, 64);
    return v;
}

// Native fp32 atomic add (global_atomic_add_f32) — NOT the CAS-loop that plain
// atomicAdd(float*) compiles to without -munsafe-fp-atomics. R2 post-mortem:
// CAS retries produced 260 MB of write traffic and ~120 us of tail serialization.
__device__ __forceinline__ void fatomic_add(float* p, float v) {
    unsafeAtomicAdd(p, v);
}

__global__ __launch_bounds__(BLOCK) void tacotron2_loss_kernel(
    const float* __restrict__ mel_out,
    const float* __restrict__ mel_post,
    const float* __restrict__ gate_out,
    const float* __restrict__ align,
    const float* __restrict__ spk_out,
    const float* __restrict__ aug_out,
    const float* __restrict__ mel_tgt,
    const float* __restrict__ gate_tgt,
    const float* __restrict__ spk_tgt,
    const float* __restrict__ aug_tgt,
    float* __restrict__ out,
    float* __restrict__ ws)
{
    float mel_s = 0.f, gate_s = 0.f, align_s = 0.f;
    const int bid = blockIdx.x;

    if (bid < MAIN_BLOCKS) {
        const int nthreads = MAIN_BLOCKS * BLOCK;
        const int tid = bid * BLOCK + threadIdx.x;
        for (int u = tid; u < U_TOTAL; u += nthreads) {
            if (u < U_MEL) {
                float4 a = ((const float4*)mel_out)[u];
                float4 p = ((const float4*)mel_post)[u];
                float4 t = ((const float4*)mel_tgt)[u];
                float d;
                d = a.x - t.x; mel_s = fmaf(d, d, mel_s);
                d = a.y - t.y; mel_s = fmaf(d, d, mel_s);
                d = a.z - t.z; mel_s = fmaf(d, d, mel_s);
                d = a.w - t.w; mel_s = fmaf(d, d, mel_s);
                d = p.x - t.x; mel_s = fmaf(d, d, mel_s);
                d = p.y - t.y; mel_s = fmaf(d, d, mel_s);
                d = p.z - t.z; mel_s = fmaf(d, d, mel_s);
                d = p.w - t.w; mel_s = fmaf(d, d, mel_s);
            } else if (u < U_MG) {
                int v = u - U_MEL;
                float4 x = ((const float4*)gate_out)[v];
                float4 y = ((const float4*)gate_tgt)[v];
                float fx[4] = {x.x, x.y, x.z, x.w};
                float fy[4] = {y.x, y.y, y.z, y.w};
#pragma unroll
                for (int j = 0; j < 4; j++) {
                    float xx = fx[j];
                    // softplus(x) = max(x,0) + log1p(exp(-|x|))
                    float sp = fmaxf(xx, 0.f) + log1pf(__expf(-fabsf(xx)));
                    gate_s += sp - xx * fy[j];
                }
            } else {
                int v = u - U_MG;
                float4 a = ((const float4*)align)[v];
                float fa[4] = {a.x, a.y, a.z, a.w};
                int e = v * 4;
                int t0 = e % TENC;                 // 4 consecutive t, same n (200 % 4 == 0)
                int n = (e / TENC) % NDEC;
                float nf = (float)n * (1.0f / (float)NDEC);
#pragma unroll
                for (int j = 0; j < 4; j++) {
                    float tf_ = (float)(t0 + j) * (1.0f / (float)TENC);
                    float d = nf - tf_;
                    float g = 1.0f - __expf(d * d * -2.5f);   // 1/K_ALIGN = 2.5
                    align_s = fmaf(fa[j], g, align_s);
                }
            }
        }
    } else {
        // CE block: wave 0 -> speaker rows, wave 1 -> augment rows.
        // Wave-reduce before atomic: 128 contended atomics -> 2.
        const int t = threadIdx.x;
        if (t < 64) {
            const int r = t;
            const float* row = spk_out + r * NSPK;
            float mx = -1e30f;
            for (int c = 0; c < NSPK; c++) mx = fmaxf(mx, row[c]);
            float se = 0.f;
            for (int c = 0; c < NSPK; c++) se += __expf(row[c] - mx);
            const float* trow = spk_tgt + r * NSPK;
            float tm = -1e30f; int lab = 0;
            for (int c = 0; c < NSPK; c++) {
                float v = trow[c];
                if (v > tm) { tm = v; lab = c; }
            }
            float loss = -(row[lab] - mx - __logf(se));
            loss = waveReduceSum(loss);
            if (t == 0) fatomic_add(&ws[WS_SPK], loss);
        } else if (t < 128) {
            const int r = t - 64;
            const float* row = aug_out + r * NAUG;
            float mx = -1e30f;
            for (int c = 0; c < NAUG; c++) mx = fmaxf(mx, row[c]);
            float se = 0.f;
            for (int c = 0; c < NAUG; c++) se += __expf(row[c] - mx);
            const float* trow = aug_tgt + r * NAUG;
            float tm = -1e30f; int lab = 0;
            for (int c = 0; c < NAUG; c++) {
                float v = trow[c];
                if (v > tm) { tm = v; lab = c; }
            }
            float loss = -(row[lab] - mx - __logf(se));
            loss = waveReduceSum(loss);
            if (t == 64) fatomic_add(&ws[WS_AUG], loss);
        }
    }

    // Block reduction of the three main sums (CE block contributes zeros)
    __shared__ float smem[12];
    const int lane = threadIdx.x & 63;
    const int wid = threadIdx.x >> 6;
    mel_s = waveReduceSum(mel_s);
    gate_s = waveReduceSum(gate_s);
    align_s = waveReduceSum(align_s);
    if (lane == 0) {
        smem[wid * 3 + 0] = mel_s;
        smem[wid * 3 + 1] = gate_s;
        smem[wid * 3 + 2] = align_s;
    }
    __syncthreads();

    if (threadIdx.x == 0) {
        float m = 0.f, g = 0.f, al = 0.f;
#pragma unroll
        for (int w = 0; w < 4; w++) {
            m += smem[w * 3 + 0];
            g += smem[w * 3 + 1];
            al += smem[w * 3 + 2];
        }
        fatomic_add(&ws[WS_MEL], m);
        fatomic_add(&ws[WS_GATE], g);
        fatomic_add(&ws[WS_ALIGN], al);
        __threadfence();
        unsigned int old = atomicAdd((unsigned int*)(ws + WS_CNT), 1u);
        if (old == gridDim.x - 1) {
            // Last block: all accumulators final. Agent-scope atomic loads
            // bypass (possibly stale) per-CU L1.
            float mel_sum   = __hip_atomic_load(&ws[WS_MEL],   __ATOMIC_RELAXED, __HIP_MEMORY_SCOPE_AGENT);
            float gate_sum  = __hip_atomic_load(&ws[WS_GATE],  __ATOMIC_RELAXED, __HIP_MEMORY_SCOPE_AGENT);
            float align_sum = __hip_atomic_load(&ws[WS_ALIGN], __ATOMIC_RELAXED, __HIP_MEMORY_SCOPE_AGENT);
            float spk_sum   = __hip_atomic_load(&ws[WS_SPK],   __ATOMIC_RELAXED, __HIP_MEMORY_SCOPE_AGENT);
            float aug_sum   = __hip_atomic_load(&ws[WS_AUG],   __ATOMIC_RELAXED, __HIP_MEMORY_SCOPE_AGENT);

            float mel_loss  = mel_sum  * (1.0f / (float)N_MEL);
            float gate_loss = gate_sum * (1.0f / (float)N_GATE);
            float spk_loss  = spk_sum  * (1.0f / (float)BATCH);
            float aug_loss  = aug_sum  * (1.0f / (float)BATCH);
            float align_loss = fabsf(align_sum) * 0.0005f;
            float tmp = mel_loss + gate_loss;
            float total = 10.0f * tmp + 0.1f * (spk_loss + aug_loss) + align_loss;

            out[0] = total;
            out[1] = tmp;
            out[2] = spk_loss;
            out[3] = aug_loss;
            out[4] = align_loss;
        }
    }
}

extern "C" void kernel_launch(void* const* d_in, const int* in_sizes, int n_in,
                              void* d_out, int out_size, void* d_ws, size_t ws_size,
                              hipStream_t stream) {
    const float* mel_out  = (const float*)d_in[0];
    const float* mel_post = (const float*)d_in[1];
    const float* gate_out = (const float*)d_in[2];
    const float* align    = (const float*)d_in[3];
    const float* spk_out  = (const float*)d_in[4];
    const float* aug_out  = (const float*)d_in[5];
    const float* mel_tgt  = (const float*)d_in[6];
    const float* gate_tgt = (const float*)d_in[7];
    const float* spk_tgt  = (const float*)d_in[8];
    const float* aug_tgt  = (const float*)d_in[9];
    // d_in[10] = step (unused by the loss values)

    float* ws = (float*)d_ws;
    float* out = (float*)d_out;

    // Zero accumulators + completion counter (harness poisons ws with 0xAA)
    hipMemsetAsync(d_ws, 0, 96 * sizeof(float), stream);

    tacotron2_loss_kernel<<<dim3(MAIN_BLOCKS + 1), dim3(BLOCK), 0, stream>>>(
        mel_out, mel_post, gate_out, align, spk_out, aug_out,
        mel_tgt, gate_tgt, spk_tgt, aug_tgt, out, ws);
}

// Round 4
// 178.649 us; speedup vs baseline: 1.4193x; 1.2518x over previous
//
#include <hip/hip_runtime.h>
#include <hip/hip_bf16.h>

// Problem constants (from reference)
#define BATCH   64
#define NMEL    80
#define TFRAME  1000
#define NDEC    1000
#define TENC    200
#define NSPK    100
#define NAUG    10

// Element counts
#define N_MEL   (BATCH * NMEL * TFRAME)     // 5,120,000
#define N_GATE  (BATCH * TFRAME)            // 64,000
#define N_ALIGN (BATCH * NDEC * TENC)       // 12,800,000

// 4-element (16 B fp32) vector units
#define U_MEL   (N_MEL / 4)                 // 1,280,000
#define U_GATE  (N_GATE / 4)                // 16,000
#define U_ALIGN (N_ALIGN / 4)               // 3,200,000
#define U_MG    (U_MEL + U_GATE)            // 1,296,000
#define U_TOTAL (U_MG + U_ALIGN)            // 4,496,000

#define MAIN_BLOCKS 2048
#define BLOCK 256

// ws layout (floats), 64 B spacing per atomic target:
//  [0]=mel_sum  [16]=gate_sum  [32]=align_sum  [48]=spk_sum  [64]=aug_sum
#define WS_MEL   0
#define WS_GATE  16
#define WS_ALIGN 32
#define WS_SPK   48
#define WS_AUG   64

__device__ __forceinline__ float waveReduceSum(float v) {
#pragma unroll
    for (int o = 32; o > 0; o >>= 1) v += __shfl_down(v, o, 64);
    return v;
}

// Native fp32 atomic add (global_atomic_add_f32). R3 proved these are
// cross-XCD correct (absmax 0.0 across 2049 blocks / 8 XCDs).
__device__ __forceinline__ void fatomic_add(float* p, float v) {
    unsafeAtomicAdd(p, v);
}

// Kernel 1: all reductions -> 5 atomic accumulators in ws.
// R4 change: NO __threadfence, NO in-kernel finalize. R3 post-mortem pinned
// ~110 us of idle-pipe time on 2049 agent-scope fences (per-XCD L2
// writeback/invalidate each). The kernel-boundary barrier now provides the
// release/acquire ordering instead.
__global__ __launch_bounds__(BLOCK) void tacotron2_loss_reduce(
    const float* __restrict__ mel_out,
    const float* __restrict__ mel_post,
    const float* __restrict__ gate_out,
    const float* __restrict__ align,
    const float* __restrict__ spk_out,
    const float* __restrict__ aug_out,
    const float* __restrict__ mel_tgt,
    const float* __restrict__ gate_tgt,
    const float* __restrict__ spk_tgt,
    const float* __restrict__ aug_tgt,
    float* __restrict__ ws)
{
    float mel_s = 0.f, gate_s = 0.f, align_s = 0.f;
    const int bid = blockIdx.x;

    if (bid < MAIN_BLOCKS) {
        const int nthreads = MAIN_BLOCKS * BLOCK;
        const int tid = bid * BLOCK + threadIdx.x;
        for (int u = tid; u < U_TOTAL; u += nthreads) {
            if (u < U_MEL) {
                float4 a = ((const float4*)mel_out)[u];
                float4 p = ((const float4*)mel_post)[u];
                float4 t = ((const float4*)mel_tgt)[u];
                float d;
                d = a.x - t.x; mel_s = fmaf(d, d, mel_s);
                d = a.y - t.y; mel_s = fmaf(d, d, mel_s);
                d = a.z - t.z; mel_s = fmaf(d, d, mel_s);
                d = a.w - t.w; mel_s = fmaf(d, d, mel_s);
                d = p.x - t.x; mel_s = fmaf(d, d, mel_s);
                d = p.y - t.y; mel_s = fmaf(d, d, mel_s);
                d = p.z - t.z; mel_s = fmaf(d, d, mel_s);
                d = p.w - t.w; mel_s = fmaf(d, d, mel_s);
            } else if (u < U_MG) {
                int v = u - U_MEL;
                float4 x = ((const float4*)gate_out)[v];
                float4 y = ((const float4*)gate_tgt)[v];
                float fx[4] = {x.x, x.y, x.z, x.w};
                float fy[4] = {y.x, y.y, y.z, y.w};
#pragma unroll
                for (int j = 0; j < 4; j++) {
                    float xx = fx[j];
                    // softplus(x) = max(x,0) + log1p(exp(-|x|))
                    float sp = fmaxf(xx, 0.f) + log1pf(__expf(-fabsf(xx)));
                    gate_s += sp - xx * fy[j];
                }
            } else {
                int v = u - U_MG;
                float4 a = ((const float4*)align)[v];
                float fa[4] = {a.x, a.y, a.z, a.w};
                int e = v * 4;
                int t0 = e % TENC;                 // 4 consecutive t, same n (200 % 4 == 0)
                int n = (e / TENC) % NDEC;
                float nf = (float)n * (1.0f / (float)NDEC);
#pragma unroll
                for (int j = 0; j < 4; j++) {
                    float tf_ = (float)(t0 + j) * (1.0f / (float)TENC);
                    float d = nf - tf_;
                    float g = 1.0f - __expf(d * d * -2.5f);   // 1/K_ALIGN = 2.5
                    align_s = fmaf(fa[j], g, align_s);
                }
            }
        }
    } else {
        // CE block: wave 0 -> speaker rows, wave 1 -> augment rows.
        const int t = threadIdx.x;
        if (t < 64) {
            const int r = t;
            const float* row = spk_out + r * NSPK;
            float mx = -1e30f;
            for (int c = 0; c < NSPK; c++) mx = fmaxf(mx, row[c]);
            float se = 0.f;
            for (int c = 0; c < NSPK; c++) se += __expf(row[c] - mx);
            const float* trow = spk_tgt + r * NSPK;
            float tm = -1e30f; int lab = 0;
            for (int c = 0; c < NSPK; c++) {
                float v = trow[c];
                if (v > tm) { tm = v; lab = c; }
            }
            float loss = -(row[lab] - mx - __logf(se));
            loss = waveReduceSum(loss);
            if (t == 0) fatomic_add(&ws[WS_SPK], loss);
        } else if (t < 128) {
            const int r = t - 64;
            const float* row = aug_out + r * NAUG;
            float mx = -1e30f;
            for (int c = 0; c < NAUG; c++) mx = fmaxf(mx, row[c]);
            float se = 0.f;
            for (int c = 0; c < NAUG; c++) se += __expf(row[c] - mx);
            const float* trow = aug_tgt + r * NAUG;
            float tm = -1e30f; int lab = 0;
            for (int c = 0; c < NAUG; c++) {
                float v = trow[c];
                if (v > tm) { tm = v; lab = c; }
            }
            float loss = -(row[lab] - mx - __logf(se));
            loss = waveReduceSum(loss);
            if (t == 64) fatomic_add(&ws[WS_AUG], loss);
        }
    }

    // Block reduction of the three main sums (CE block contributes zeros)
    __shared__ float smem[12];
    const int lane = threadIdx.x & 63;
    const int wid = threadIdx.x >> 6;
    mel_s = waveReduceSum(mel_s);
    gate_s = waveReduceSum(gate_s);
    align_s = waveReduceSum(align_s);
    if (lane == 0) {
        smem[wid * 3 + 0] = mel_s;
        smem[wid * 3 + 1] = gate_s;
        smem[wid * 3 + 2] = align_s;
    }
    __syncthreads();

    if (threadIdx.x == 0) {
        float m = 0.f, g = 0.f, al = 0.f;
#pragma unroll
        for (int w = 0; w < 4; w++) {
            m += smem[w * 3 + 0];
            g += smem[w * 3 + 1];
            al += smem[w * 3 + 2];
        }
        fatomic_add(&ws[WS_MEL], m);
        fatomic_add(&ws[WS_GATE], g);
        fatomic_add(&ws[WS_ALIGN], al);
    }
}

// Kernel 2: finalize. One block; kernel boundary = release/acquire, so the
// atomics from kernel 1 are visible. Agent-scope atomic loads bypass L1.
__global__ __launch_bounds__(64) void tacotron2_loss_finalize(
    const float* __restrict__ ws, float* __restrict__ out)
{
    if (threadIdx.x == 0) {
        float mel_sum   = __hip_atomic_load(&ws[WS_MEL],   __ATOMIC_RELAXED, __HIP_MEMORY_SCOPE_AGENT);
        float gate_sum  = __hip_atomic_load(&ws[WS_GATE],  __ATOMIC_RELAXED, __HIP_MEMORY_SCOPE_AGENT);
        float align_sum = __hip_atomic_load(&ws[WS_ALIGN], __ATOMIC_RELAXED, __HIP_MEMORY_SCOPE_AGENT);
        float spk_sum   = __hip_atomic_load(&ws[WS_SPK],   __ATOMIC_RELAXED, __HIP_MEMORY_SCOPE_AGENT);
        float aug_sum   = __hip_atomic_load(&ws[WS_AUG],   __ATOMIC_RELAXED, __HIP_MEMORY_SCOPE_AGENT);

        float mel_loss  = mel_sum  * (1.0f / (float)N_MEL);
        float gate_loss = gate_sum * (1.0f / (float)N_GATE);
        float spk_loss  = spk_sum  * (1.0f / (float)BATCH);
        float aug_loss  = aug_sum  * (1.0f / (float)BATCH);
        float align_loss = fabsf(align_sum) * 0.0005f;
        float tmp = mel_loss + gate_loss;
        float total = 10.0f * tmp + 0.1f * (spk_loss + aug_loss) + align_loss;

        out[0] = total;
        out[1] = tmp;
        out[2] = spk_loss;
        out[3] = aug_loss;
        out[4] = align_loss;
    }
}

extern "C" void kernel_launch(void* const* d_in, const int* in_sizes, int n_in,
                              void* d_out, int out_size, void* d_ws, size_t ws_size,
                              hipStream_t stream) {
    const float* mel_out  = (const float*)d_in[0];
    const float* mel_post = (const float*)d_in[1];
    const float* gate_out = (const float*)d_in[2];
    const float* align    = (const float*)d_in[3];
    const float* spk_out  = (const float*)d_in[4];
    const float* aug_out  = (const float*)d_in[5];
    const float* mel_tgt  = (const float*)d_in[6];
    const float* gate_tgt = (const float*)d_in[7];
    const float* spk_tgt  = (const float*)d_in[8];
    const float* aug_tgt  = (const float*)d_in[9];
    // d_in[10] = step (unused by the loss values)

    float* ws = (float*)d_ws;
    float* out = (float*)d_out;

    // Zero accumulators (harness poisons ws with 0xAA)
    hipMemsetAsync(d_ws, 0, 80 * sizeof(float), stream);

    tacotron2_loss_reduce<<<dim3(MAIN_BLOCKS + 1), dim3(BLOCK), 0, stream>>>(
        mel_out, mel_post, gate_out, align, spk_out, aug_out,
        mel_tgt, gate_tgt, spk_tgt, aug_tgt, ws);

    tacotron2_loss_finalize<<<dim3(1), dim3(64), 0, stream>>>(ws, out);
}